// Round 6
// baseline (420.190 us; speedup 1.0000x reference)
//
#include <hip/hip_runtime.h>
#include <hip/hip_bf16.h>

#define N_NODES 50000
#define N_EDGES 800000
#define N_TOT   (N_EDGES + N_NODES)
#define N_GRAPHS 256
#define F_IN 310
#define KP1 320          // F_IN padded to multiple of 32
#define CH 256
#define HID 128
#define DEG_CAP 128      // per-wave LDS edge cache (avg deg ~17; P(deg>128) ~ 0)

typedef __attribute__((ext_vector_type(8))) short short8;
typedef __attribute__((ext_vector_type(4))) float f32x4;
typedef unsigned short ushort_t;

__device__ __forceinline__ float selu_f(float x) {
    const float scale = 1.0507009873554805f;
    const float alpha = 1.6732632423543772f;
    return x > 0.f ? scale * x : scale * alpha * (expm1f(x));
}

__device__ __forceinline__ ushort_t f32_to_bf16_rne(float f) {
    unsigned u = __float_as_uint(f);
    unsigned rounding = 0x7FFFu + ((u >> 16) & 1u);
    return (ushort_t)((u + rounding) >> 16);
}
__device__ __forceinline__ float bf16_to_f32(ushort_t v) {
    return __uint_as_float(((unsigned)v) << 16);
}

// ---- convert x [N, 310] f32 -> A [N, 320] bf16 (block per row) -------------
__global__ __launch_bounds__(256) void convert_pad_x(
        const float* __restrict__ x, ushort_t* __restrict__ A) {
    int r = blockIdx.x;
    const float* xr = x + (long)r * F_IN;
    ushort_t* Ar = A + (long)r * KP1;
    for (int c = threadIdx.x; c < KP1; c += 256)
        Ar[c] = (c < F_IN) ? f32_to_bf16_rne(xr[c]) : 0;
}

// ---- W [K, 256] f32 -> Wt [256, Kp] bf16 (transposed, zero-padded) ---------
__global__ __launch_bounds__(256) void convert_wt(
        const float* __restrict__ W, ushort_t* __restrict__ Wt, int K, int Kp) {
    int i = blockIdx.x * blockDim.x + threadIdx.x;
    if (i >= CH * Kp) return;
    int n = i / Kp, k = i % Kp;
    Wt[i] = (k < K) ? f32_to_bf16_rne(W[(long)k * CH + n]) : 0;
}

// ------- MFMA GEMM + fused attention-scalar epilogue ------------------------
__global__ __launch_bounds__(256) void gemm_bf16_fused(
        const ushort_t* __restrict__ A, const ushort_t* __restrict__ Bt,
        ushort_t* __restrict__ Cb, const float* __restrict__ att_l,
        const float* __restrict__ att_r, float* __restrict__ a_src,
        float* __restrict__ a_dst, int M, int Kp) {
    __shared__ __align__(16) ushort_t As[128 * 32];
    __shared__ __align__(16) ushort_t Bs[128 * 32];
    int tid = threadIdx.x;
    int col0 = blockIdx.x * 128;
    int row0 = blockIdx.y * 128;
    int w = tid >> 6, l = tid & 63;
    int lr = l & 15, lc = l >> 4;
    f32x4 acc[2][8] = {};
    int sr = tid >> 2;
    int sc = tid & 3;

    for (int k0 = 0; k0 < Kp; k0 += 32) {
#pragma unroll
        for (int i = 0; i < 2; i++) {
            int r = sr + i * 64;
            int grow = row0 + r;
            int4 av = {0, 0, 0, 0};
            if (grow < M) av = *(const int4*)(A + (size_t)grow * Kp + k0 + sc * 8);
            *(int4*)(As + r * 32 + ((sc ^ (r & 3)) * 8)) = av;
            int4 bv = *(const int4*)(Bt + (size_t)(col0 + r) * Kp + k0 + sc * 8);
            *(int4*)(Bs + r * 32 + ((sc ^ (r & 3)) * 8)) = bv;
        }
        __syncthreads();
        short8 af[2], bf[8];
#pragma unroll
        for (int mi = 0; mi < 2; mi++) {
            int r = w * 32 + mi * 16 + lr;
            af[mi] = *(const short8*)(As + r * 32 + ((lc ^ (r & 3)) * 8));
        }
#pragma unroll
        for (int ni = 0; ni < 8; ni++) {
            int r = ni * 16 + lr;
            bf[ni] = *(const short8*)(Bs + r * 32 + ((lc ^ (r & 3)) * 8));
        }
#pragma unroll
        for (int mi = 0; mi < 2; mi++)
#pragma unroll
            for (int ni = 0; ni < 8; ni++)
                acc[mi][ni] = __builtin_amdgcn_mfma_f32_16x16x32_bf16(
                    af[mi], bf[ni], acc[mi][ni], 0, 0, 0);
        __syncthreads();
    }
    float al[8], ar[8];
#pragma unroll
    for (int ni = 0; ni < 8; ni++) {
        int col = col0 + ni * 16 + lr;
        al[ni] = att_l[col];
        ar[ni] = att_r[col];
    }
#pragma unroll
    for (int mi = 0; mi < 2; mi++) {
        int rbase = row0 + w * 32 + mi * 16 + lc * 4;
#pragma unroll
        for (int q = 0; q < 4; q++) {
            int grow = rbase + q;
            float pl = 0.f, pr = 0.f;
#pragma unroll
            for (int ni = 0; ni < 8; ni++) {
                float v = acc[mi][ni][q];
                pl += v * al[ni];
                pr += v * ar[ni];
                if (grow < M) Cb[(size_t)grow * CH + col0 + ni * 16 + lr] = f32_to_bf16_rne(v);
            }
#pragma unroll
            for (int off = 1; off < 16; off <<= 1) {
                pl += __shfl_xor(pl, off);
                pr += __shfl_xor(pr, off);
            }
            if (lr == 0 && grow < M) {
                atomicAdd(&a_src[grow], pl);
                atomicAdd(&a_dst[grow], pr);
            }
        }
    }
}

// ---------------- CSR build: deg count -> range reserve -> fill -------------
__global__ __launch_bounds__(256) void deg_count(
        const int* __restrict__ ei, int* __restrict__ deg) {
    int eid = blockIdx.x * blockDim.x + threadIdx.x;
    if (eid >= N_TOT) return;
    int d = (eid < N_EDGES) ? ei[N_EDGES + eid] : eid - N_EDGES;
    atomicAdd(&deg[d], 1);
}

__global__ __launch_bounds__(256) void reserve_k(
        const int* __restrict__ deg, int* __restrict__ start,
        int* __restrict__ fillpos, int* __restrict__ cursor, int n) {
    int i = blockIdx.x * blockDim.x + threadIdx.x;
    if (i >= n) return;
    int s = atomicAdd(cursor, deg[i]);
    start[i] = s;
    fillpos[i] = s;
}

__global__ __launch_bounds__(256) void csr_fill(
        const int* __restrict__ ei, int* __restrict__ fillpos,
        int* __restrict__ csr_src) {
    int eid = blockIdx.x * blockDim.x + threadIdx.x;
    if (eid >= N_TOT) return;
    int s, d;
    if (eid < N_EDGES) { s = ei[eid]; d = ei[N_EDGES + eid]; }
    else { s = eid - N_EDGES; d = s; }
    int p = atomicAdd(&fillpos[d], 1);
    csr_src[p] = s;
}

// ---- fused per-dst softmax + bf16 gather-accumulate ------------------------
// one wave per node (4 waves/block). Sweeps 1-2 build (src, exp) in LDS.
// Gather pass: half-wave split — each 32-lane half owns alternate edges,
// each lane covers 8 channels (16B dwordx4 loads); x4 unroll = 8 gathers
// in flight per wave. Halves merged via shfl_xor(32).
__global__ __launch_bounds__(256) void gat_aggregate(
        const int* __restrict__ start, const int* __restrict__ deg,
        const int* __restrict__ csr_src,
        const float* __restrict__ a_src, const float* __restrict__ a_dst,
        const ushort_t* __restrict__ h, const float* __restrict__ bias,
        float* __restrict__ out_f32, ushort_t* __restrict__ out_bf, int n) {
    __shared__ int   s_idx[4][DEG_CAP];
    __shared__ float s_ex[4][DEG_CAP];
    int wid = threadIdx.x >> 6;
    int lane = threadIdx.x & 63;
    int node = blockIdx.x * 4 + wid;
    if (node >= n) return;
    int s0 = start[node];
    int dg = deg[node];
    float ad = a_dst[node];
    bool cached = (dg <= DEG_CAP);

    // sweep 1: compute e per edge once, stash (s, e) in LDS; lane max
    float m = -1e30f;
    for (int i = lane; i < dg; i += 64) {
        int s = csr_src[s0 + i];
        float e = a_src[s] + ad;
        e = e > 0.f ? e : 0.2f * e;
        if (cached) { s_idx[wid][i] = s; s_ex[wid][i] = e; }
        m = fmaxf(m, e);
    }
#pragma unroll
    for (int off = 32; off > 0; off >>= 1) m = fmaxf(m, __shfl_xor(m, off));

    // sweep 2: e -> exp(e-m) in LDS; lane sum
    float sum = 0.f;
    if (cached) {
        for (int i = lane; i < dg; i += 64) {
            float ex = __expf(s_ex[wid][i] - m);
            s_ex[wid][i] = ex;
            sum += ex;
        }
    } else {
        for (int i = lane; i < dg; i += 64) {
            int s = csr_src[s0 + i];
            float e = a_src[s] + ad;
            e = e > 0.f ? e : 0.2f * e;
            sum += __expf(e - m);
        }
    }
#pragma unroll
    for (int off = 32; off > 0; off >>= 1) sum += __shfl_xor(sum, off);
    float inv = 1.f / fmaxf(sum, 1e-16f);

    // pass 3: half-wave edge split, 8 ch/lane, 16B gathers
    int half = lane >> 5;
    int ch0 = (lane & 31) * 8;
    float acc[8] = {};
    if (cached) {
        int i = half;
        for (; i + 6 < dg; i += 8) {
            int sa = s_idx[wid][i],     sb = s_idx[wid][i + 2];
            int sc_ = s_idx[wid][i + 4], sd = s_idx[wid][i + 6];
            float xa = s_ex[wid][i] * inv,     xb = s_ex[wid][i + 2] * inv;
            float xc = s_ex[wid][i + 4] * inv, xd = s_ex[wid][i + 6] * inv;
            short8 ha = *(const short8*)(h + (long)sa * CH + ch0);
            short8 hb = *(const short8*)(h + (long)sb * CH + ch0);
            short8 hc = *(const short8*)(h + (long)sc_ * CH + ch0);
            short8 hd = *(const short8*)(h + (long)sd * CH + ch0);
#pragma unroll
            for (int c = 0; c < 8; c++) {
                acc[c] += xa * bf16_to_f32((ushort_t)ha[c])
                        + xb * bf16_to_f32((ushort_t)hb[c])
                        + xc * bf16_to_f32((ushort_t)hc[c])
                        + xd * bf16_to_f32((ushort_t)hd[c]);
            }
        }
        for (; i < dg; i += 2) {
            int s = s_idx[wid][i];
            float xa = s_ex[wid][i] * inv;
            short8 hv = *(const short8*)(h + (long)s * CH + ch0);
#pragma unroll
            for (int c = 0; c < 8; c++) acc[c] += xa * bf16_to_f32((ushort_t)hv[c]);
        }
    } else {
        for (int i = half; i < dg; i += 2) {
            int s = csr_src[s0 + i];
            float e = a_src[s] + ad;
            e = e > 0.f ? e : 0.2f * e;
            float xa = __expf(e - m) * inv;
            short8 hv = *(const short8*)(h + (long)s * CH + ch0);
#pragma unroll
            for (int c = 0; c < 8; c++) acc[c] += xa * bf16_to_f32((ushort_t)hv[c]);
        }
    }
    // merge the two halves (same channels, alternate edges)
#pragma unroll
    for (int c = 0; c < 8; c++) acc[c] += __shfl_xor(acc[c], 32);

    if (half == 0) {
        float o[8];
#pragma unroll
        for (int c = 0; c < 8; c++) o[c] = selu_f(acc[c] + bias[ch0 + c]);
        if (out_f32) {
            float4 o0 = {o[0], o[1], o[2], o[3]};
            float4 o1 = {o[4], o[5], o[6], o[7]};
            *(float4*)(out_f32 + (long)node * CH + ch0) = o0;
            *(float4*)(out_f32 + (long)node * CH + ch0 + 4) = o1;
        }
        if (out_bf) {
            short8 ob;
#pragma unroll
            for (int c = 0; c < 8; c++) ob[c] = (short)f32_to_bf16_rne(o[c]);
            *(short8*)(out_bf + (long)node * CH + ch0) = ob;
        }
    }
}

// ---- pool (bf16 input): batch SORTED -> per-graph segment via binary search
__global__ __launch_bounds__(256) void pool_kernel(
        const ushort_t* __restrict__ h, const int* __restrict__ batch,
        float* __restrict__ g1) {
    int g = blockIdx.x;
    int t = threadIdx.x;
    int lo, hi;
    { int a = 0, b = N_NODES;
      while (a < b) { int mid = (a + b) >> 1; if (batch[mid] < g) a = mid + 1; else b = mid; }
      lo = a; }
    { int a = lo, b = N_NODES;
      while (a < b) { int mid = (a + b) >> 1; if (batch[mid] < g + 1) a = mid + 1; else b = mid; }
      hi = a; }
    float acc = 0.f;
    for (int i = lo; i < hi; i++) acc += bf16_to_f32(h[(long)i * CH + t]);
    float cnt = (float)(hi - lo);
    g1[g * CH + t] = selu_f(acc / fmaxf(cnt, 1.f));
}

// ---- head: selu(g1 @ fc1 + b1) @ fc2 + b2 -> log_softmax -------------------
__global__ __launch_bounds__(128) void head_kernel(
        const float* __restrict__ g1, const float* __restrict__ fc1W,
        const float* __restrict__ fc1b, const float* __restrict__ fc2W,
        const float* __restrict__ fc2b, float* __restrict__ out) {
    __shared__ float row[CH];
    __shared__ float hrow[HID];
    __shared__ float logits[2];
    int g = blockIdx.x, t = threadIdx.x;
    row[t] = g1[g * CH + t];
    row[t + 128] = g1[g * CH + t + 128];
    __syncthreads();
    float acc = fc1b[t];
    for (int k = 0; k < CH; k++) acc += row[k] * fc1W[k * HID + t];
    hrow[t] = selu_f(acc);
    __syncthreads();
    if (t < 2) {
        float a = fc2b[t];
        for (int k = 0; k < HID; k++) a += hrow[k] * fc2W[k * 2 + t];
        logits[t] = a;
    }
    __syncthreads();
    if (t < 2) {
        float m = fmaxf(logits[0], logits[1]);
        float lse = logf(expf(logits[0] - m) + expf(logits[1] - m)) + m;
        out[g * 2 + t] = logits[t] - lse;
    }
}

extern "C" void kernel_launch(void* const* d_in, const int* in_sizes, int n_in,
                              void* d_out, int out_size, void* d_ws, size_t ws_size,
                              hipStream_t stream) {
    const float* x      = (const float*)d_in[0];
    const int*   ei     = (const int*)d_in[1];
    const int*   batch  = (const int*)d_in[2];
    const float* W1     = (const float*)d_in[3];
    const float* att_l1 = (const float*)d_in[4];
    const float* att_r1 = (const float*)d_in[5];
    const float* b1     = (const float*)d_in[6];
    const float* W2     = (const float*)d_in[7];
    const float* att_l2 = (const float*)d_in[8];
    const float* att_r2 = (const float*)d_in[9];
    const float* b2     = (const float*)d_in[10];
    const float* fc1W   = (const float*)d_in[11];
    const float* fc1b   = (const float*)d_in[12];
    const float* fc2W   = (const float*)d_in[13];
    const float* fc2b   = (const float*)d_in[14];
    float* out = (float*)d_out;

    char* ws = (char*)d_ws;
    size_t off = 0;
    auto alloc = [&](size_t bytes) {
        void* p = ws + off;
        off += (bytes + 255) & ~(size_t)255;
        return p;
    };
    ushort_t* Ab     = (ushort_t*)alloc((size_t)N_NODES * KP1 * 2);
    ushort_t* Hb1    = (ushort_t*)alloc((size_t)N_NODES * CH * 2);   // GEMM1 out; reused as agg2 out
    ushort_t* Zb2    = (ushort_t*)alloc((size_t)N_NODES * CH * 2);   // agg1 out = GEMM2 in
    ushort_t* Hb2    = (ushort_t*)alloc((size_t)N_NODES * CH * 2);   // GEMM2 out
    ushort_t* W1t    = (ushort_t*)alloc((size_t)CH * KP1 * 2);
    ushort_t* W2t    = (ushort_t*)alloc((size_t)CH * CH * 2);
    float*    a_src  = (float*)alloc((size_t)N_NODES * 4);
    float*    a_dst  = (float*)alloc((size_t)N_NODES * 4);
    int*      deg    = (int*)alloc((size_t)N_NODES * 4);
    int*      startA = (int*)alloc((size_t)N_NODES * 4);
    int*      fillpos= (int*)alloc((size_t)N_NODES * 4);
    int*      csr_src= (int*)alloc((size_t)N_TOT * 4);
    int*      cursor = (int*)alloc(256);
    float*    g1     = (float*)alloc((size_t)N_GRAPHS * CH * 4);

    // a_src and a_dst are adjacent (each padded to 200192B): one memset covers both
    size_t a_pair_bytes = (size_t)((char*)a_dst - (char*)a_src) + (size_t)N_NODES * 4;

    dim3 blk(256);
    dim3 gemm_grid(CH / 128, (N_NODES + 127) / 128);
    int edge_grid = (N_TOT + 255) / 256;
    int node_grid = (N_NODES + 255) / 256;
    int agg_grid  = (N_NODES + 3) / 4;

    // ---------------- input conversions + CSR build ----------------
    convert_pad_x<<<N_NODES, blk, 0, stream>>>(x, Ab);
    convert_wt<<<(CH * KP1 + 255) / 256, blk, 0, stream>>>(W1, W1t, F_IN, KP1);
    convert_wt<<<(CH * CH + 255) / 256, blk, 0, stream>>>(W2, W2t, CH, CH);
    hipMemsetAsync(deg, 0, (size_t)N_NODES * 4, stream);
    hipMemsetAsync(cursor, 0, 4, stream);
    deg_count<<<edge_grid, blk, 0, stream>>>(ei, deg);
    reserve_k<<<node_grid, blk, 0, stream>>>(deg, startA, fillpos, cursor, N_NODES);
    csr_fill<<<edge_grid, blk, 0, stream>>>(ei, fillpos, csr_src);

    // ---------------- Layer 1 ----------------
    hipMemsetAsync(a_src, 0, a_pair_bytes, stream);
    gemm_bf16_fused<<<gemm_grid, blk, 0, stream>>>(Ab, W1t, Hb1, att_l1, att_r1,
                                                   a_src, a_dst, N_NODES, KP1);
    gat_aggregate<<<agg_grid, blk, 0, stream>>>(startA, deg, csr_src, a_src, a_dst,
                                                Hb1, b1, (float*)nullptr, Zb2, N_NODES);

    // ---------------- Layer 2 ----------------
    hipMemsetAsync(a_src, 0, a_pair_bytes, stream);
    gemm_bf16_fused<<<gemm_grid, blk, 0, stream>>>(Zb2, W2t, Hb2, att_l2, att_r2,
                                                   a_src, a_dst, N_NODES, CH);
    gat_aggregate<<<agg_grid, blk, 0, stream>>>(startA, deg, csr_src, a_src, a_dst,
                                                Hb2, b2, (float*)nullptr, Hb1, N_NODES);

    // ---------------- Pool + head ----------------
    pool_kernel<<<N_GRAPHS, blk, 0, stream>>>(Hb1, batch, g1);
    head_kernel<<<N_GRAPHS, dim3(128), 0, stream>>>(g1, fc1W, fc1b, fc2W, fc2b, out);
}

// Round 7
// 388.535 us; speedup vs baseline: 1.0815x; 1.0815x over previous
//
#include <hip/hip_runtime.h>
#include <hip/hip_bf16.h>

#define N_NODES 50000
#define N_EDGES 800000
#define N_TOT   (N_EDGES + N_NODES)
#define N_GRAPHS 256
#define F_IN 310
#define KP1 320          // F_IN padded to multiple of 32
#define CH 256
#define HID 128
#define DEG_CAP 128      // per-wave LDS edge cache (avg deg ~17; P(deg>128) ~ 0)

typedef __attribute__((ext_vector_type(8))) short short8;
typedef __attribute__((ext_vector_type(4))) float f32x4;
typedef unsigned short ushort_t;

__device__ __forceinline__ float selu_f(float x) {
    const float scale = 1.0507009873554805f;
    const float alpha = 1.6732632423543772f;
    return x > 0.f ? scale * x : scale * alpha * (expm1f(x));
}

__device__ __forceinline__ ushort_t f32_to_bf16_rne(float f) {
    unsigned u = __float_as_uint(f);
    unsigned rounding = 0x7FFFu + ((u >> 16) & 1u);
    return (ushort_t)((u + rounding) >> 16);
}
__device__ __forceinline__ float bf16_to_f32(ushort_t v) {
    return __uint_as_float(((unsigned)v) << 16);
}

// ---- convert x [N, 310] f32 -> A [N, 320] bf16 (block per row) -------------
__global__ __launch_bounds__(256) void convert_pad_x(
        const float* __restrict__ x, ushort_t* __restrict__ A) {
    int r = blockIdx.x;
    const float* xr = x + (long)r * F_IN;
    ushort_t* Ar = A + (long)r * KP1;
    for (int c = threadIdx.x; c < KP1; c += 256)
        Ar[c] = (c < F_IN) ? f32_to_bf16_rne(xr[c]) : 0;
}

// ---- W [K, 256] f32 -> Wt [256, Kp] bf16 (transposed, zero-padded) ---------
__global__ __launch_bounds__(256) void convert_wt(
        const float* __restrict__ W, ushort_t* __restrict__ Wt, int K, int Kp) {
    int i = blockIdx.x * blockDim.x + threadIdx.x;
    if (i >= CH * Kp) return;
    int n = i / Kp, k = i % Kp;
    Wt[i] = (k < K) ? f32_to_bf16_rne(W[(long)k * CH + n]) : 0;
}

// ------- MFMA GEMM (global_load_lds staging) + fused att-scalar epilogue ----
// C[M,256] = A[M,Kp]bf16 @ Wt[256,Kp]^T -> bf16, plus a_src/a_dst partials.
// Staging: global_load_lds width=16, LINEAR LDS dest (wave base + lane*16);
// the XOR chunk-swizzle (c ^ (r&3)) is applied to the per-lane GLOBAL source,
// reads use the same XOR (involution) -> both-sides-consistent (rule #21).
__global__ __launch_bounds__(256) void gemm_bf16_fused(
        const ushort_t* __restrict__ A, const ushort_t* __restrict__ Bt,
        ushort_t* __restrict__ Cb, const float* __restrict__ att_l,
        const float* __restrict__ att_r, float* __restrict__ a_src,
        float* __restrict__ a_dst, int M, int Kp) {
    __shared__ __align__(16) ushort_t As[128 * 32];
    __shared__ __align__(16) ushort_t Bs[128 * 32];
    int tid = threadIdx.x;
    int col0 = blockIdx.x * 128;
    int row0 = blockIdx.y * 128;
    int w = tid >> 6, l = tid & 63;
    int lr = l & 15, lc = l >> 4;
    f32x4 acc[2][8] = {};

    // staging geometry: wave w owns tile rows [w*32, w*32+32) as two 16-row
    // groups; lane l -> row = group + (l>>2), chunk (l&3); source chunk
    // pre-swizzled so LDS content is lds[r][j] = global chunk j ^ (r&3).
    int srow = l >> 2;
    int sxor = (l & 3) ^ (srow & 3);

    for (int k0 = 0; k0 < Kp; k0 += 32) {
#pragma unroll
        for (int g = 0; g < 2; g++) {
            int r = w * 32 + g * 16 + srow;          // tile row (r&3 == srow&3)
            int garow = row0 + r;
            if (garow >= M) garow = M - 1;           // clamp: dup rows never stored
            const ushort_t* ga = A + (size_t)garow * Kp + k0 + sxor * 8;
            __builtin_amdgcn_global_load_lds(
                (const __attribute__((address_space(1))) void*)ga,
                (__attribute__((address_space(3))) void*)(As + (w * 32 + g * 16) * 32),
                16, 0, 0);
            const ushort_t* gb = Bt + (size_t)(col0 + r) * Kp + k0 + sxor * 8;
            __builtin_amdgcn_global_load_lds(
                (const __attribute__((address_space(1))) void*)gb,
                (__attribute__((address_space(3))) void*)(Bs + (w * 32 + g * 16) * 32),
                16, 0, 0);
        }
        __syncthreads();
        short8 af[2], bf[8];
#pragma unroll
        for (int mi = 0; mi < 2; mi++) {
            int r = w * 32 + mi * 16 + lr;
            af[mi] = *(const short8*)(As + r * 32 + ((lc ^ (r & 3)) * 8));
        }
#pragma unroll
        for (int ni = 0; ni < 8; ni++) {
            int r = ni * 16 + lr;
            bf[ni] = *(const short8*)(Bs + r * 32 + ((lc ^ (r & 3)) * 8));
        }
#pragma unroll
        for (int mi = 0; mi < 2; mi++)
#pragma unroll
            for (int ni = 0; ni < 8; ni++)
                acc[mi][ni] = __builtin_amdgcn_mfma_f32_16x16x32_bf16(
                    af[mi], bf[ni], acc[mi][ni], 0, 0, 0);
        __syncthreads();
    }
    float al[8], ar[8];
#pragma unroll
    for (int ni = 0; ni < 8; ni++) {
        int col = col0 + ni * 16 + lr;
        al[ni] = att_l[col];
        ar[ni] = att_r[col];
    }
#pragma unroll
    for (int mi = 0; mi < 2; mi++) {
        int rbase = row0 + w * 32 + mi * 16 + lc * 4;
#pragma unroll
        for (int q = 0; q < 4; q++) {
            int grow = rbase + q;
            float pl = 0.f, pr = 0.f;
#pragma unroll
            for (int ni = 0; ni < 8; ni++) {
                float v = acc[mi][ni][q];
                pl += v * al[ni];
                pr += v * ar[ni];
                if (grow < M) Cb[(size_t)grow * CH + col0 + ni * 16 + lr] = f32_to_bf16_rne(v);
            }
#pragma unroll
            for (int off = 1; off < 16; off <<= 1) {
                pl += __shfl_xor(pl, off);
                pr += __shfl_xor(pr, off);
            }
            if (lr == 0 && grow < M) {
                atomicAdd(&a_src[grow], pl);
                atomicAdd(&a_dst[grow], pr);
            }
        }
    }
}

// ---------------- CSR build: deg count -> range reserve -> fill -------------
__global__ __launch_bounds__(256) void deg_count(
        const int* __restrict__ ei, int* __restrict__ deg) {
    int eid = blockIdx.x * blockDim.x + threadIdx.x;
    if (eid >= N_TOT) return;
    int d = (eid < N_EDGES) ? ei[N_EDGES + eid] : eid - N_EDGES;
    atomicAdd(&deg[d], 1);
}

__global__ __launch_bounds__(256) void reserve_k(
        const int* __restrict__ deg, int* __restrict__ start,
        int* __restrict__ fillpos, int* __restrict__ cursor, int n) {
    int i = blockIdx.x * blockDim.x + threadIdx.x;
    if (i >= n) return;
    int s = atomicAdd(cursor, deg[i]);
    start[i] = s;
    fillpos[i] = s;
}

__global__ __launch_bounds__(256) void csr_fill(
        const int* __restrict__ ei, int* __restrict__ fillpos,
        int* __restrict__ csr_src) {
    int eid = blockIdx.x * blockDim.x + threadIdx.x;
    if (eid >= N_TOT) return;
    int s, d;
    if (eid < N_EDGES) { s = ei[eid]; d = ei[N_EDGES + eid]; }
    else { s = eid - N_EDGES; d = s; }
    int p = atomicAdd(&fillpos[d], 1);
    csr_src[p] = s;
}

// ---- fused per-dst softmax + bf16 gather-accumulate, LDS edge cache --------
// one wave per node (4 waves/block); (src, exp) stashed in LDS; gather pass
// full-wave (4 ch/lane, ushort4) with x4 edge unroll (round-5 winner).
__global__ __launch_bounds__(256) void gat_aggregate(
        const int* __restrict__ start, const int* __restrict__ deg,
        const int* __restrict__ csr_src,
        const float* __restrict__ a_src, const float* __restrict__ a_dst,
        const ushort_t* __restrict__ h, const float* __restrict__ bias,
        ushort_t* __restrict__ out_bf, int n) {
    __shared__ int   s_idx[4][DEG_CAP];
    __shared__ float s_ex[4][DEG_CAP];
    int wid = threadIdx.x >> 6;
    int lane = threadIdx.x & 63;
    int node = blockIdx.x * 4 + wid;
    if (node >= n) return;
    int s0 = start[node];
    int dg = deg[node];
    float ad = a_dst[node];
    bool cached = (dg <= DEG_CAP);

    // sweep 1: compute e per edge once, stash (s, e) in LDS; lane max
    float m = -1e30f;
    for (int i = lane; i < dg; i += 64) {
        int s = csr_src[s0 + i];
        float e = a_src[s] + ad;
        e = e > 0.f ? e : 0.2f * e;
        if (cached) { s_idx[wid][i] = s; s_ex[wid][i] = e; }
        m = fmaxf(m, e);
    }
#pragma unroll
    for (int off = 32; off > 0; off >>= 1) m = fmaxf(m, __shfl_xor(m, off));

    // sweep 2: e -> exp(e-m) in LDS; lane sum
    float sum = 0.f;
    if (cached) {
        for (int i = lane; i < dg; i += 64) {
            float ex = __expf(s_ex[wid][i] - m);
            s_ex[wid][i] = ex;
            sum += ex;
        }
    } else {
        for (int i = lane; i < dg; i += 64) {
            int s = csr_src[s0 + i];
            float e = a_src[s] + ad;
            e = e > 0.f ? e : 0.2f * e;
            sum += __expf(e - m);
        }
    }
#pragma unroll
    for (int off = 32; off > 0; off >>= 1) sum += __shfl_xor(sum, off);
    float inv = 1.f / fmaxf(sum, 1e-16f);

    // pass 3: alpha from LDS; 4 gathers in flight; 4 ch/lane (ushort4)
    float4 acc = {0.f, 0.f, 0.f, 0.f};
    if (cached) {
        int i = 0;
        for (; i + 4 <= dg; i += 4) {
            int sa = s_idx[wid][i],     sb = s_idx[wid][i + 1];
            int sc_ = s_idx[wid][i + 2], sd = s_idx[wid][i + 3];
            float xa = s_ex[wid][i] * inv,     xb = s_ex[wid][i + 1] * inv;
            float xc = s_ex[wid][i + 2] * inv, xd = s_ex[wid][i + 3] * inv;
            ushort4 ha = *(const ushort4*)(h + (long)sa * CH + lane * 4);
            ushort4 hb = *(const ushort4*)(h + (long)sb * CH + lane * 4);
            ushort4 hc = *(const ushort4*)(h + (long)sc_ * CH + lane * 4);
            ushort4 hd = *(const ushort4*)(h + (long)sd * CH + lane * 4);
            acc.x += xa * bf16_to_f32(ha.x) + xb * bf16_to_f32(hb.x)
                   + xc * bf16_to_f32(hc.x) + xd * bf16_to_f32(hd.x);
            acc.y += xa * bf16_to_f32(ha.y) + xb * bf16_to_f32(hb.y)
                   + xc * bf16_to_f32(hc.y) + xd * bf16_to_f32(hd.y);
            acc.z += xa * bf16_to_f32(ha.z) + xb * bf16_to_f32(hb.z)
                   + xc * bf16_to_f32(hc.z) + xd * bf16_to_f32(hd.z);
            acc.w += xa * bf16_to_f32(ha.w) + xb * bf16_to_f32(hb.w)
                   + xc * bf16_to_f32(hc.w) + xd * bf16_to_f32(hd.w);
        }
        for (; i < dg; i++) {
            int s = s_idx[wid][i];
            float xa = s_ex[wid][i] * inv;
            ushort4 hv = *(const ushort4*)(h + (long)s * CH + lane * 4);
            acc.x += xa * bf16_to_f32(hv.x);
            acc.y += xa * bf16_to_f32(hv.y);
            acc.z += xa * bf16_to_f32(hv.z);
            acc.w += xa * bf16_to_f32(hv.w);
        }
    } else {
        for (int i = 0; i < dg; i++) {
            int s = csr_src[s0 + i];
            float e = a_src[s] + ad;
            e = e > 0.f ? e : 0.2f * e;
            float alpha = __expf(e - m) * inv;
            ushort4 hv = *(const ushort4*)(h + (long)s * CH + lane * 4);
            acc.x += alpha * bf16_to_f32(hv.x);
            acc.y += alpha * bf16_to_f32(hv.y);
            acc.z += alpha * bf16_to_f32(hv.z);
            acc.w += alpha * bf16_to_f32(hv.w);
        }
    }
    float4 bv = *(const float4*)(bias + lane * 4);
    ushort4 ob;
    ob.x = f32_to_bf16_rne(selu_f(acc.x + bv.x));
    ob.y = f32_to_bf16_rne(selu_f(acc.y + bv.y));
    ob.z = f32_to_bf16_rne(selu_f(acc.z + bv.z));
    ob.w = f32_to_bf16_rne(selu_f(acc.w + bv.w));
    *(ushort4*)(out_bf + (long)node * CH + lane * 4) = ob;
}

// ---- pool (bf16 input): batch SORTED -> per-graph segment via binary search
__global__ __launch_bounds__(256) void pool_kernel(
        const ushort_t* __restrict__ h, const int* __restrict__ batch,
        float* __restrict__ g1) {
    int g = blockIdx.x;
    int t = threadIdx.x;
    int lo, hi;
    { int a = 0, b = N_NODES;
      while (a < b) { int mid = (a + b) >> 1; if (batch[mid] < g) a = mid + 1; else b = mid; }
      lo = a; }
    { int a = lo, b = N_NODES;
      while (a < b) { int mid = (a + b) >> 1; if (batch[mid] < g + 1) a = mid + 1; else b = mid; }
      hi = a; }
    float acc = 0.f;
    for (int i = lo; i < hi; i++) acc += bf16_to_f32(h[(long)i * CH + t]);
    float cnt = (float)(hi - lo);
    g1[g * CH + t] = selu_f(acc / fmaxf(cnt, 1.f));
}

// ---- head: selu(g1 @ fc1 + b1) @ fc2 + b2 -> log_softmax -------------------
__global__ __launch_bounds__(128) void head_kernel(
        const float* __restrict__ g1, const float* __restrict__ fc1W,
        const float* __restrict__ fc1b, const float* __restrict__ fc2W,
        const float* __restrict__ fc2b, float* __restrict__ out) {
    __shared__ float row[CH];
    __shared__ float hrow[HID];
    __shared__ float logits[2];
    int g = blockIdx.x, t = threadIdx.x;
    row[t] = g1[g * CH + t];
    row[t + 128] = g1[g * CH + t + 128];
    __syncthreads();
    float acc = fc1b[t];
    for (int k = 0; k < CH; k++) acc += row[k] * fc1W[k * HID + t];
    hrow[t] = selu_f(acc);
    __syncthreads();
    if (t < 2) {
        float a = fc2b[t];
        for (int k = 0; k < HID; k++) a += hrow[k] * fc2W[k * 2 + t];
        logits[t] = a;
    }
    __syncthreads();
    if (t < 2) {
        float m = fmaxf(logits[0], logits[1]);
        float lse = logf(expf(logits[0] - m) + expf(logits[1] - m)) + m;
        out[g * 2 + t] = logits[t] - lse;
    }
}

extern "C" void kernel_launch(void* const* d_in, const int* in_sizes, int n_in,
                              void* d_out, int out_size, void* d_ws, size_t ws_size,
                              hipStream_t stream) {
    const float* x      = (const float*)d_in[0];
    const int*   ei     = (const int*)d_in[1];
    const int*   batch  = (const int*)d_in[2];
    const float* W1     = (const float*)d_in[3];
    const float* att_l1 = (const float*)d_in[4];
    const float* att_r1 = (const float*)d_in[5];
    const float* b1     = (const float*)d_in[6];
    const float* W2     = (const float*)d_in[7];
    const float* att_l2 = (const float*)d_in[8];
    const float* att_r2 = (const float*)d_in[9];
    const float* b2     = (const float*)d_in[10];
    const float* fc1W   = (const float*)d_in[11];
    const float* fc1b   = (const float*)d_in[12];
    const float* fc2W   = (const float*)d_in[13];
    const float* fc2b   = (const float*)d_in[14];
    float* out = (float*)d_out;

    char* ws = (char*)d_ws;
    size_t off = 0;
    auto alloc = [&](size_t bytes) {
        void* p = ws + off;
        off += (bytes + 255) & ~(size_t)255;
        return p;
    };
    ushort_t* Ab     = (ushort_t*)alloc((size_t)N_NODES * KP1 * 2);
    ushort_t* Hb1    = (ushort_t*)alloc((size_t)N_NODES * CH * 2);   // GEMM1 out; reused as agg2 out
    ushort_t* Zb2    = (ushort_t*)alloc((size_t)N_NODES * CH * 2);   // agg1 out = GEMM2 in
    ushort_t* Hb2    = (ushort_t*)alloc((size_t)N_NODES * CH * 2);   // GEMM2 out
    ushort_t* W1t    = (ushort_t*)alloc((size_t)CH * KP1 * 2);
    ushort_t* W2t    = (ushort_t*)alloc((size_t)CH * CH * 2);
    float*    a_src  = (float*)alloc((size_t)N_NODES * 4);
    float*    a_dst  = (float*)alloc((size_t)N_NODES * 4);
    int*      deg    = (int*)alloc((size_t)N_NODES * 4);
    int*      startA = (int*)alloc((size_t)N_NODES * 4);
    int*      fillpos= (int*)alloc((size_t)N_NODES * 4);
    int*      csr_src= (int*)alloc((size_t)N_TOT * 4);
    int*      cursor = (int*)alloc(256);
    float*    g1     = (float*)alloc((size_t)N_GRAPHS * CH * 4);

    size_t a_pair_bytes = (size_t)((char*)a_dst - (char*)a_src) + (size_t)N_NODES * 4;

    dim3 blk(256);
    dim3 gemm_grid(CH / 128, (N_NODES + 127) / 128);
    int edge_grid = (N_TOT + 255) / 256;
    int node_grid = (N_NODES + 255) / 256;
    int agg_grid  = (N_NODES + 3) / 4;

    // ---------------- input conversions + CSR build ----------------
    convert_pad_x<<<N_NODES, blk, 0, stream>>>(x, Ab);
    convert_wt<<<(CH * KP1 + 255) / 256, blk, 0, stream>>>(W1, W1t, F_IN, KP1);
    convert_wt<<<(CH * CH + 255) / 256, blk, 0, stream>>>(W2, W2t, CH, CH);
    hipMemsetAsync(deg, 0, (size_t)N_NODES * 4, stream);
    hipMemsetAsync(cursor, 0, 4, stream);
    deg_count<<<edge_grid, blk, 0, stream>>>(ei, deg);
    reserve_k<<<node_grid, blk, 0, stream>>>(deg, startA, fillpos, cursor, N_NODES);
    csr_fill<<<edge_grid, blk, 0, stream>>>(ei, fillpos, csr_src);

    // ---------------- Layer 1 ----------------
    hipMemsetAsync(a_src, 0, a_pair_bytes, stream);
    gemm_bf16_fused<<<gemm_grid, blk, 0, stream>>>(Ab, W1t, Hb1, att_l1, att_r1,
                                                   a_src, a_dst, N_NODES, KP1);
    gat_aggregate<<<agg_grid, blk, 0, stream>>>(startA, deg, csr_src, a_src, a_dst,
                                                Hb1, b1, Zb2, N_NODES);

    // ---------------- Layer 2 ----------------
    hipMemsetAsync(a_src, 0, a_pair_bytes, stream);
    gemm_bf16_fused<<<gemm_grid, blk, 0, stream>>>(Zb2, W2t, Hb2, att_l2, att_r2,
                                                   a_src, a_dst, N_NODES, CH);
    gat_aggregate<<<agg_grid, blk, 0, stream>>>(startA, deg, csr_src, a_src, a_dst,
                                                Hb2, b2, Hb1, N_NODES);

    // ---------------- Pool + head ----------------
    pool_kernel<<<N_GRAPHS, blk, 0, stream>>>(Hb1, batch, g1);
    head_kernel<<<N_GRAPHS, dim3(128), 0, stream>>>(g1, fc1W, fc1b, fc2W, fc2b, out);
}

// Round 8
// 325.738 us; speedup vs baseline: 1.2900x; 1.1928x over previous
//
#include <hip/hip_runtime.h>
#include <hip/hip_bf16.h>

#define N_NODES 50000
#define N_EDGES 800000
#define N_TOT   (N_EDGES + N_NODES)
#define N_GRAPHS 256
#define F_IN 310
#define KP1 320          // F_IN padded to multiple of 32
#define CH 256
#define HID 128
#define DEG_CAP 128      // per-wave LDS edge cache (avg deg ~17; P(deg>128) ~ 0)

typedef __attribute__((ext_vector_type(8))) short short8;
typedef __attribute__((ext_vector_type(4))) float f32x4;
typedef unsigned short ushort_t;

__device__ __forceinline__ float selu_f(float x) {
    const float scale = 1.0507009873554805f;
    const float alpha = 1.6732632423543772f;
    return x > 0.f ? scale * x : scale * alpha * (expm1f(x));
}

__device__ __forceinline__ ushort_t f32_to_bf16_rne(float f) {
    unsigned u = __float_as_uint(f);
    unsigned rounding = 0x7FFFu + ((u >> 16) & 1u);
    return (ushort_t)((u + rounding) >> 16);
}
__device__ __forceinline__ float bf16_to_f32(ushort_t v) {
    return __uint_as_float(((unsigned)v) << 16);
}

// ---- convert x [N, 310] f32 -> A [N, 320] bf16, float2-vectorized ----------
// flat index over N*160 ushort2 slots; cols 310..319 zero-padded.
__global__ __launch_bounds__(256) void convert_pad_x(
        const float* __restrict__ x, ushort_t* __restrict__ A) {
    int i = blockIdx.x * 256 + threadIdx.x;
    if (i >= N_NODES * (KP1 / 2)) return;
    int r = i / (KP1 / 2);
    int c2 = i - r * (KP1 / 2);
    int c = c2 * 2;
    ushort2 o = {0, 0};
    if (c2 < F_IN / 2) {
        float2 v = *(const float2*)(x + (long)r * F_IN + c);
        o.x = f32_to_bf16_rne(v.x);
        o.y = f32_to_bf16_rne(v.y);
    }
    *(ushort2*)(A + (long)r * KP1 + c) = o;
}

// ---- W [K, 256] f32 -> Wt [256, Kp] bf16 (transposed, zero-padded) ---------
__global__ __launch_bounds__(256) void convert_wt(
        const float* __restrict__ W, ushort_t* __restrict__ Wt, int K, int Kp) {
    int i = blockIdx.x * blockDim.x + threadIdx.x;
    if (i >= CH * Kp) return;
    int n = i / Kp, k = i % Kp;
    Wt[i] = (k < K) ? f32_to_bf16_rne(W[(long)k * CH + n]) : 0;
}

// ------- MFMA GEMM 128x256 tile, 512 thr, 2-phase glds pipeline -------------
// C[M,256] = A[M,Kp]bf16 @ Wt[256,Kp]^T -> bf16. Full output width per block:
// A staged once; a_src/a_dst written directly (no atomics, no memset).
// Double-buffered LDS; stage(t+1) issued before compute(t); one barrier/K-step
// (__syncthreads drains vmcnt). Chunk swizzle c^(r&3) applied to the GLOBAL
// source with linear glds dest; reads use the same XOR (involution, rule #21).
__global__ __launch_bounds__(512) void gemm_bf16_fused(
        const ushort_t* __restrict__ A, const ushort_t* __restrict__ Bt,
        ushort_t* __restrict__ Cb, const float* __restrict__ att_l,
        const float* __restrict__ att_r, float* __restrict__ a_src,
        float* __restrict__ a_dst, int M, int Kp) {
    __shared__ __align__(16) ushort_t As[2][128 * 32];
    __shared__ __align__(16) ushort_t Bs[2][256 * 32];
    int tid = threadIdx.x;
    int row0 = blockIdx.x * 128;
    int w = tid >> 6, l = tid & 63;
    int lr = l & 15, lc = l >> 4;
    f32x4 acc[16] = {};

    // staging: wave w owns A rows [w*16, w*16+16) and B rows w*16+{0,128}
    int srow = l >> 2;                 // 0..15
    int schunk = l & 3;
    int trowA = w * 16 + srow;         // tile row; trowA&3 == srow&3
    int sx = schunk ^ (srow & 3);      // pre-swizzled source chunk
    int garow = row0 + trowA; if (garow >= M) garow = M - 1;   // clamp (dup rows never stored)
    const ushort_t* gA  = A  + (size_t)garow * Kp + sx * 8;
    const ushort_t* gB0 = Bt + (size_t)trowA * Kp + sx * 8;
    const ushort_t* gB1 = Bt + (size_t)(128 + trowA) * Kp + sx * 8;
    int nt = Kp >> 5;

    auto stage = [&](int sel, int k0) {
        __builtin_amdgcn_global_load_lds(
            (const __attribute__((address_space(1))) void*)(gA + k0),
            (__attribute__((address_space(3))) void*)(&As[sel][w * 16 * 32]), 16, 0, 0);
        __builtin_amdgcn_global_load_lds(
            (const __attribute__((address_space(1))) void*)(gB0 + k0),
            (__attribute__((address_space(3))) void*)(&Bs[sel][w * 16 * 32]), 16, 0, 0);
        __builtin_amdgcn_global_load_lds(
            (const __attribute__((address_space(1))) void*)(gB1 + k0),
            (__attribute__((address_space(3))) void*)(&Bs[sel][(128 + w * 16) * 32]), 16, 0, 0);
    };

    stage(0, 0);
    __syncthreads();                   // vmcnt(0) drain -> buf 0 ready
    int cur = 0;
    for (int t = 0; t < nt; ++t) {
        if (t + 1 < nt) stage(cur ^ 1, (t + 1) << 5);   // async prefetch
        int rA = w * 16 + lr;
        short8 af = *(const short8*)(&As[cur][rA * 32 + ((lc ^ (rA & 3)) * 8)]);
#pragma unroll
        for (int hn = 0; hn < 2; ++hn) {
            short8 bf[8];
#pragma unroll
            for (int nj = 0; nj < 8; ++nj) {
                int r = (hn * 8 + nj) * 16 + lr;
                bf[nj] = *(const short8*)(&Bs[cur][r * 32 + ((lc ^ (r & 3)) * 8)]);
            }
#pragma unroll
            for (int nj = 0; nj < 8; ++nj)
                acc[hn * 8 + nj] = __builtin_amdgcn_mfma_f32_16x16x32_bf16(
                    af, bf[nj], acc[hn * 8 + nj], 0, 0, 0);
        }
        __syncthreads();               // all reads done + prefetch drained
        cur ^= 1;
    }

    // epilogue: C/D col = lane&15, row = (lane>>4)*4 + q
    float al[16], ar[16];
#pragma unroll
    for (int ni = 0; ni < 16; ++ni) {
        int col = ni * 16 + lr;
        al[ni] = att_l[col];
        ar[ni] = att_r[col];
    }
    int rbase = row0 + w * 16 + lc * 4;
#pragma unroll
    for (int q = 0; q < 4; ++q) {
        int grow = rbase + q;
        float pl = 0.f, pr = 0.f;
#pragma unroll
        for (int ni = 0; ni < 16; ++ni) {
            float v = acc[ni][q];
            pl += v * al[ni];
            pr += v * ar[ni];
            if (grow < M) Cb[(size_t)grow * CH + ni * 16 + lr] = f32_to_bf16_rne(v);
        }
#pragma unroll
        for (int off = 1; off < 16; off <<= 1) {
            pl += __shfl_xor(pl, off);
            pr += __shfl_xor(pr, off);
        }
        if (lr == 0 && grow < M) {
            a_src[grow] = pl;          // direct store: full row owned by this block
            a_dst[grow] = pr;
        }
    }
}

// ---------------- CSR build: deg count -> range reserve -> fill -------------
__global__ __launch_bounds__(256) void deg_count(
        const int* __restrict__ ei, int* __restrict__ deg) {
    int eid = blockIdx.x * blockDim.x + threadIdx.x;
    if (eid >= N_TOT) return;
    int d = (eid < N_EDGES) ? ei[N_EDGES + eid] : eid - N_EDGES;
    atomicAdd(&deg[d], 1);
}

__global__ __launch_bounds__(256) void reserve_k(
        const int* __restrict__ deg, int* __restrict__ start,
        int* __restrict__ fillpos, int* __restrict__ cursor, int n) {
    int i = blockIdx.x * blockDim.x + threadIdx.x;
    if (i >= n) return;
    int s = atomicAdd(cursor, deg[i]);
    start[i] = s;
    fillpos[i] = s;
}

__global__ __launch_bounds__(256) void csr_fill(
        const int* __restrict__ ei, int* __restrict__ fillpos,
        int* __restrict__ csr_src) {
    int eid = blockIdx.x * blockDim.x + threadIdx.x;
    if (eid >= N_TOT) return;
    int s, d;
    if (eid < N_EDGES) { s = ei[eid]; d = ei[N_EDGES + eid]; }
    else { s = eid - N_EDGES; d = s; }
    int p = atomicAdd(&fillpos[d], 1);
    csr_src[p] = s;
}

// ---- fused per-dst softmax + bf16 gather-accumulate, LDS edge cache --------
// one wave per node (4 waves/block); (src, exp) stashed in LDS; gather pass
// full-wave (4 ch/lane, ushort4) with x4 edge unroll (round-5/7 winner).
__global__ __launch_bounds__(256) void gat_aggregate(
        const int* __restrict__ start, const int* __restrict__ deg,
        const int* __restrict__ csr_src,
        const float* __restrict__ a_src, const float* __restrict__ a_dst,
        const ushort_t* __restrict__ h, const float* __restrict__ bias,
        ushort_t* __restrict__ out_bf, int n) {
    __shared__ int   s_idx[4][DEG_CAP];
    __shared__ float s_ex[4][DEG_CAP];
    int wid = threadIdx.x >> 6;
    int lane = threadIdx.x & 63;
    int node = blockIdx.x * 4 + wid;
    if (node >= n) return;
    int s0 = start[node];
    int dg = deg[node];
    float ad = a_dst[node];
    bool cached = (dg <= DEG_CAP);

    float m = -1e30f;
    for (int i = lane; i < dg; i += 64) {
        int s = csr_src[s0 + i];
        float e = a_src[s] + ad;
        e = e > 0.f ? e : 0.2f * e;
        if (cached) { s_idx[wid][i] = s; s_ex[wid][i] = e; }
        m = fmaxf(m, e);
    }
#pragma unroll
    for (int off = 32; off > 0; off >>= 1) m = fmaxf(m, __shfl_xor(m, off));

    float sum = 0.f;
    if (cached) {
        for (int i = lane; i < dg; i += 64) {
            float ex = __expf(s_ex[wid][i] - m);
            s_ex[wid][i] = ex;
            sum += ex;
        }
    } else {
        for (int i = lane; i < dg; i += 64) {
            int s = csr_src[s0 + i];
            float e = a_src[s] + ad;
            e = e > 0.f ? e : 0.2f * e;
            sum += __expf(e - m);
        }
    }
#pragma unroll
    for (int off = 32; off > 0; off >>= 1) sum += __shfl_xor(sum, off);
    float inv = 1.f / fmaxf(sum, 1e-16f);

    float4 acc = {0.f, 0.f, 0.f, 0.f};
    if (cached) {
        int i = 0;
        for (; i + 4 <= dg; i += 4) {
            int sa = s_idx[wid][i],     sb = s_idx[wid][i + 1];
            int sc_ = s_idx[wid][i + 2], sd = s_idx[wid][i + 3];
            float xa = s_ex[wid][i] * inv,     xb = s_ex[wid][i + 1] * inv;
            float xc = s_ex[wid][i + 2] * inv, xd = s_ex[wid][i + 3] * inv;
            ushort4 ha = *(const ushort4*)(h + (long)sa * CH + lane * 4);
            ushort4 hb = *(const ushort4*)(h + (long)sb * CH + lane * 4);
            ushort4 hc = *(const ushort4*)(h + (long)sc_ * CH + lane * 4);
            ushort4 hd = *(const ushort4*)(h + (long)sd * CH + lane * 4);
            acc.x += xa * bf16_to_f32(ha.x) + xb * bf16_to_f32(hb.x)
                   + xc * bf16_to_f32(hc.x) + xd * bf16_to_f32(hd.x);
            acc.y += xa * bf16_to_f32(ha.y) + xb * bf16_to_f32(hb.y)
                   + xc * bf16_to_f32(hc.y) + xd * bf16_to_f32(hd.y);
            acc.z += xa * bf16_to_f32(ha.z) + xb * bf16_to_f32(hb.z)
                   + xc * bf16_to_f32(hc.z) + xd * bf16_to_f32(hd.z);
            acc.w += xa * bf16_to_f32(ha.w) + xb * bf16_to_f32(hb.w)
                   + xc * bf16_to_f32(hc.w) + xd * bf16_to_f32(hd.w);
        }
        for (; i < dg; i++) {
            int s = s_idx[wid][i];
            float xa = s_ex[wid][i] * inv;
            ushort4 hv = *(const ushort4*)(h + (long)s * CH + lane * 4);
            acc.x += xa * bf16_to_f32(hv.x);
            acc.y += xa * bf16_to_f32(hv.y);
            acc.z += xa * bf16_to_f32(hv.z);
            acc.w += xa * bf16_to_f32(hv.w);
        }
    } else {
        for (int i = 0; i < dg; i++) {
            int s = csr_src[s0 + i];
            float e = a_src[s] + ad;
            e = e > 0.f ? e : 0.2f * e;
            float alpha = __expf(e - m) * inv;
            ushort4 hv = *(const ushort4*)(h + (long)s * CH + lane * 4);
            acc.x += alpha * bf16_to_f32(hv.x);
            acc.y += alpha * bf16_to_f32(hv.y);
            acc.z += alpha * bf16_to_f32(hv.z);
            acc.w += alpha * bf16_to_f32(hv.w);
        }
    }
    float4 bv = *(const float4*)(bias + lane * 4);
    ushort4 ob;
    ob.x = f32_to_bf16_rne(selu_f(acc.x + bv.x));
    ob.y = f32_to_bf16_rne(selu_f(acc.y + bv.y));
    ob.z = f32_to_bf16_rne(selu_f(acc.z + bv.z));
    ob.w = f32_to_bf16_rne(selu_f(acc.w + bv.w));
    *(ushort4*)(out_bf + (long)node * CH + lane * 4) = ob;
}

// ---- pool (bf16 input): batch SORTED -> per-graph segment, x4 unrolled -----
__global__ __launch_bounds__(256) void pool_kernel(
        const ushort_t* __restrict__ h, const int* __restrict__ batch,
        float* __restrict__ g1) {
    int g = blockIdx.x;
    int t = threadIdx.x;
    int lo, hi;
    { int a = 0, b = N_NODES;
      while (a < b) { int mid = (a + b) >> 1; if (batch[mid] < g) a = mid + 1; else b = mid; }
      lo = a; }
    { int a = lo, b = N_NODES;
      while (a < b) { int mid = (a + b) >> 1; if (batch[mid] < g + 1) a = mid + 1; else b = mid; }
      hi = a; }
    float a0 = 0.f, a1 = 0.f, a2 = 0.f, a3 = 0.f;
    int i = lo;
    for (; i + 3 < hi; i += 4) {
        a0 += bf16_to_f32(h[(long)i * CH + t]);
        a1 += bf16_to_f32(h[(long)(i + 1) * CH + t]);
        a2 += bf16_to_f32(h[(long)(i + 2) * CH + t]);
        a3 += bf16_to_f32(h[(long)(i + 3) * CH + t]);
    }
    for (; i < hi; i++) a0 += bf16_to_f32(h[(long)i * CH + t]);
    float acc = (a0 + a1) + (a2 + a3);
    float cnt = (float)(hi - lo);
    g1[g * CH + t] = selu_f(acc / fmaxf(cnt, 1.f));
}

// ---- head: selu(g1 @ fc1 + b1) @ fc2 + b2 -> log_softmax -------------------
__global__ __launch_bounds__(128) void head_kernel(
        const float* __restrict__ g1, const float* __restrict__ fc1W,
        const float* __restrict__ fc1b, const float* __restrict__ fc2W,
        const float* __restrict__ fc2b, float* __restrict__ out) {
    __shared__ float row[CH];
    __shared__ float hrow[HID];
    __shared__ float logits[2];
    int g = blockIdx.x, t = threadIdx.x;
    row[t] = g1[g * CH + t];
    row[t + 128] = g1[g * CH + t + 128];
    __syncthreads();
    float acc = fc1b[t];
    for (int k = 0; k < CH; k++) acc += row[k] * fc1W[k * HID + t];
    hrow[t] = selu_f(acc);
    __syncthreads();
    if (t < 2) {
        float a = fc2b[t];
        for (int k = 0; k < HID; k++) a += hrow[k] * fc2W[k * 2 + t];
        logits[t] = a;
    }
    __syncthreads();
    if (t < 2) {
        float m = fmaxf(logits[0], logits[1]);
        float lse = logf(expf(logits[0] - m) + expf(logits[1] - m)) + m;
        out[g * 2 + t] = logits[t] - lse;
    }
}

extern "C" void kernel_launch(void* const* d_in, const int* in_sizes, int n_in,
                              void* d_out, int out_size, void* d_ws, size_t ws_size,
                              hipStream_t stream) {
    const float* x      = (const float*)d_in[0];
    const int*   ei     = (const int*)d_in[1];
    const int*   batch  = (const int*)d_in[2];
    const float* W1     = (const float*)d_in[3];
    const float* att_l1 = (const float*)d_in[4];
    const float* att_r1 = (const float*)d_in[5];
    const float* b1     = (const float*)d_in[6];
    const float* W2     = (const float*)d_in[7];
    const float* att_l2 = (const float*)d_in[8];
    const float* att_r2 = (const float*)d_in[9];
    const float* b2     = (const float*)d_in[10];
    const float* fc1W   = (const float*)d_in[11];
    const float* fc1b   = (const float*)d_in[12];
    const float* fc2W   = (const float*)d_in[13];
    const float* fc2b   = (const float*)d_in[14];
    float* out = (float*)d_out;

    char* ws = (char*)d_ws;
    size_t off = 0;
    auto alloc = [&](size_t bytes) {
        void* p = ws + off;
        off += (bytes + 255) & ~(size_t)255;
        return p;
    };
    ushort_t* Ab     = (ushort_t*)alloc((size_t)N_NODES * KP1 * 2);
    ushort_t* Hb1    = (ushort_t*)alloc((size_t)N_NODES * CH * 2);   // GEMM1 out; reused as agg2 out
    ushort_t* Zb2    = (ushort_t*)alloc((size_t)N_NODES * CH * 2);   // agg1 out = GEMM2 in
    ushort_t* Hb2    = (ushort_t*)alloc((size_t)N_NODES * CH * 2);   // GEMM2 out
    ushort_t* W1t    = (ushort_t*)alloc((size_t)CH * KP1 * 2);
    ushort_t* W2t    = (ushort_t*)alloc((size_t)CH * CH * 2);
    float*    a_src  = (float*)alloc((size_t)N_NODES * 4);
    float*    a_dst  = (float*)alloc((size_t)N_NODES * 4);
    int*      deg    = (int*)alloc((size_t)N_NODES * 4);
    int*      startA = (int*)alloc((size_t)N_NODES * 4);
    int*      fillpos= (int*)alloc((size_t)N_NODES * 4);
    int*      csr_src= (int*)alloc((size_t)N_TOT * 4);
    int*      cursor = (int*)alloc(256);
    float*    g1     = (float*)alloc((size_t)N_GRAPHS * CH * 4);

    dim3 blk(256);
    int gemm_grid = (N_NODES + 127) / 128;      // 391 blocks, 512 thr each
    int conv_grid = (N_NODES * (KP1 / 2) + 255) / 256;
    int edge_grid = (N_TOT + 255) / 256;
    int node_grid = (N_NODES + 255) / 256;
    int agg_grid  = (N_NODES + 3) / 4;

    // ---------------- input conversions + CSR build ----------------
    convert_pad_x<<<conv_grid, blk, 0, stream>>>(x, Ab);
    convert_wt<<<(CH * KP1 + 255) / 256, blk, 0, stream>>>(W1, W1t, F_IN, KP1);
    convert_wt<<<(CH * CH + 255) / 256, blk, 0, stream>>>(W2, W2t, CH, CH);
    hipMemsetAsync(deg, 0, (size_t)N_NODES * 4, stream);
    hipMemsetAsync(cursor, 0, 4, stream);
    deg_count<<<edge_grid, blk, 0, stream>>>(ei, deg);
    reserve_k<<<node_grid, blk, 0, stream>>>(deg, startA, fillpos, cursor, N_NODES);
    csr_fill<<<edge_grid, blk, 0, stream>>>(ei, fillpos, csr_src);

    // ---------------- Layer 1 ----------------
    gemm_bf16_fused<<<gemm_grid, dim3(512), 0, stream>>>(Ab, W1t, Hb1, att_l1, att_r1,
                                                         a_src, a_dst, N_NODES, KP1);
    gat_aggregate<<<agg_grid, blk, 0, stream>>>(startA, deg, csr_src, a_src, a_dst,
                                                Hb1, b1, Zb2, N_NODES);

    // ---------------- Layer 2 ----------------
    gemm_bf16_fused<<<gemm_grid, dim3(512), 0, stream>>>(Zb2, W2t, Hb2, att_l2, att_r2,
                                                         a_src, a_dst, N_NODES, CH);
    gat_aggregate<<<agg_grid, blk, 0, stream>>>(startA, deg, csr_src, a_src, a_dst,
                                                Hb2, b2, Hb1, N_NODES);

    // ---------------- Pool + head ----------------
    pool_kernel<<<N_GRAPHS, blk, 0, stream>>>(Hb1, batch, g1);
    head_kernel<<<N_GRAPHS, dim3(128), 0, stream>>>(g1, fc1W, fc1b, fc2W, fc2b, out);
}